// Round 5
// baseline (402.008 us; speedup 1.0000x reference)
//
#include <hip/hip_runtime.h>
#include <math.h>

// LIF first-spike time, closed form:
//   a = 0.8 ; n = max(ceil(log(1-1/I)/log(a)), 1) ; t = 0.01*n ; I<=1 -> sentinel
//
// R4 post-mortem: kernel ~137us, still marginally VALU-bound. Minimal-VALU form:
//   nr = (log2(I-1) - log2(I)) * (1/log2(0.8))   [2x v_log_f32, I-1 Sterbenz-exact]
// Removed (with proofs, not data-dependence):
//  - "n <= 200000" test: any fp32 I>1 has I-1 >= 2^-23 -> nr <= ~72 << 2e5. Always true.
//  - bit-scrub: select is (cur>1) ? nn*0.01 : SENT; true side has nn in [1,72]
//    (fmaxf lowers to IEEE v_max_f32: max(NaN,1)=1, max(+inf...)-- only at cur==1,
//    where the cur>1 predicate picks SENT). Both sides finite by construction.
//  - NOTE the cur>1.0f compare is LOAD-BEARING: v_max_f32 eats NaN (returns 1),
//    so NaN-propagation does NOT mask non-firing lanes. Keep it.
// Non-temporal stores: output is write-once/never-read; keep it out of L2/L3 so
// the L3 keeps serving the input (FETCH_SIZE 125MB < 256MB input = L3 retention).

#define SENTINEL_F 1.0e30f
#define C_NR (-3.1062837f) /* 1 / log2(0.8f) */

typedef float vfloat4 __attribute__((ext_vector_type(4)));

__device__ __forceinline__ float spike_time_min(float cur) {
    float la = __log2f(cur - 1.0f);     // v_log_f32; NaN (cur<1) / -inf (cur==1)
    float lb = __log2f(cur);            // v_log_f32
    float nr = fmaf(la, C_NR, lb * (-C_NR));   // mul + fma
    float nn = fmaxf(ceilf(nr), 1.0f);         // v_rndup + v_max (IEEE: eats NaN)
    return (cur > 1.0f) ? nn * 0.01f : SENTINEL_F;  // v_cmp + v_mul + v_cndmask
}

__global__ __launch_bounds__(256) void lif_spike_v5(const float* __restrict__ in,
                                                    float* __restrict__ out,
                                                    int nelem) {
    const long long gid0 = (long long)blockIdx.x * blockDim.x + threadIdx.x;
    const long long gstride = (long long)gridDim.x * blockDim.x;
    const long long nvec = nelem >> 2;

    const vfloat4* __restrict__ in4 = (const vfloat4*)in;
    vfloat4* __restrict__ out4 = (vfloat4*)out;

    for (long long i = gid0; i < nvec; i += gstride) {
        vfloat4 v = in4[i];                       // cached load (L3-friendly)
        vfloat4 r;
        r.x = spike_time_min(v.x);
        r.y = spike_time_min(v.y);
        r.z = spike_time_min(v.z);
        r.w = spike_time_min(v.w);
        __builtin_nontemporal_store(r, &out4[i]); // global_store_dwordx4 nt
    }
    // tail (empty for 64M, kept for generality)
    for (long long i = (nvec << 2) + gid0; i < nelem; i += gstride) {
        out[i] = spike_time_min(in[i]);
    }
}

__global__ __launch_bounds__(256) void lif_spike_v5_scalar(const float* __restrict__ in,
                                                           float* __restrict__ out,
                                                           int nelem) {
    const long long gid0 = (long long)blockIdx.x * blockDim.x + threadIdx.x;
    const long long gstride = (long long)gridDim.x * blockDim.x;
    for (long long i = gid0; i < nelem; i += gstride) {
        out[i] = spike_time_min(in[i]);
    }
}

extern "C" void kernel_launch(void* const* d_in, const int* in_sizes, int n_in,
                              void* d_out, int out_size, void* d_ws, size_t ws_size,
                              hipStream_t stream) {
    const float* in = (const float*)d_in[0];
    float* out = (float*)d_out;
    const int n = in_sizes[0]; // 64 * 1,000,000 fp32

    const bool aligned16 = ((((uintptr_t)in) | ((uintptr_t)out)) & 0xF) == 0;

    if (aligned16 && (n & 3) == 0) {
        const int block = 256;
        long long nvec = n >> 2;
        long long grid = (nvec + block - 1) / block; // 62,500 for 64M
        if (grid < 1) grid = 1;
        if (grid > 1048576) grid = 1048576;
        lif_spike_v5<<<(int)grid, block, 0, stream>>>(in, out, n);
    } else {
        const int block = 256;
        long long grid = (n + block - 1) / block;
        if (grid < 1) grid = 1;
        if (grid > 1048576) grid = 1048576;
        lif_spike_v5_scalar<<<(int)grid, block, 0, stream>>>(in, out, n);
    }
}